// Round 2
// baseline (754.387 us; speedup 1.0000x reference)
//
#include <hip/hip_runtime.h>
#include <hip/hip_bf16.h>
#include <cmath>

// SparseAttentionBlock: B=2, L=4096, D=512, H=8, dh=64
// Inputs/outputs fp32 (per reference dtypes); internal GEMM pipeline in bf16,
// residual spine in fp32.

#define L_SEQ 4096
#define D_MODEL 512
#define N_HEADS 8
#define D_HEAD 64
#define QKV_LD 1536

typedef __attribute__((ext_vector_type(8))) short bf16x8;
typedef __attribute__((ext_vector_type(4))) float f32x4;

__device__ __forceinline__ __hip_bfloat16 f2bf(float v) { return __float2bfloat16(v); }
__device__ __forceinline__ float bf2f(__hip_bfloat16 v) { return __bfloat162float(v); }

__device__ __forceinline__ void gl_lds16(const __hip_bfloat16* g, __hip_bfloat16* l) {
  __builtin_amdgcn_global_load_lds((__attribute__((address_space(1))) void*)g,
                                   (__attribute__((address_space(3))) void*)l, 16, 0, 0);
}

// ---------------- fp32 -> bf16 convert (weights) ----------------
__global__ __launch_bounds__(256) void cvt_kernel(const float* __restrict__ src,
                                                  __hip_bfloat16* __restrict__ dst, int n4) {
  const int i = blockIdx.x * 256 + threadIdx.x;
  if (i < n4) {
    const float4 v = ((const float4*)src)[i];
    dst[4 * i + 0] = f2bf(v.x);
    dst[4 * i + 1] = f2bf(v.y);
    dst[4 * i + 2] = f2bf(v.z);
    dst[4 * i + 3] = f2bf(v.w);
  }
}

// ---------------- LayerNorm: fp32 in -> bf16 out ----------------
__global__ __launch_bounds__(256) void ln_kernel(const float* __restrict__ x,
                                                 const float* __restrict__ g,
                                                 const float* __restrict__ b,
                                                 __hip_bfloat16* __restrict__ out) {
  const int row = blockIdx.x;
  const int t = threadIdx.x;
  const float* xr = x + (size_t)row * D_MODEL;
  float v0 = xr[t];
  float v1 = xr[t + 256];
  float s = v0 + v1;
  float qq = v0 * v0 + v1 * v1;
  for (int off = 32; off > 0; off >>= 1) {
    s += __shfl_xor(s, off);
    qq += __shfl_xor(qq, off);
  }
  __shared__ float red[8];
  const int wid = t >> 6;
  if ((t & 63) == 0) { red[wid] = s; red[4 + wid] = qq; }
  __syncthreads();
  s = red[0] + red[1] + red[2] + red[3];
  qq = red[4] + red[5] + red[6] + red[7];
  const float mu = s * (1.0f / 512.0f);
  const float var = fmaxf(qq * (1.0f / 512.0f) - mu * mu, 0.0f);
  const float rstd = rsqrtf(var + 1e-5f);
  __hip_bfloat16* orow = out + (size_t)row * D_MODEL;
  orow[t] = f2bf((v0 - mu) * rstd * g[t] + b[t]);
  orow[t + 256] = f2bf((v1 - mu) * rstd * g[t + 256] + b[t + 256]);
}

// ---------------- GEMM: C[M,N] = A[M,K] @ B[N,K]^T, bf16 in, fp32 accum ----------------
// EPI 0: store bf16                      1: += aux(fp32), store fp32
// EPI 2: silu, store bf16                3: += aux(fp32), store fp32
template <int EPI>
__global__ __launch_bounds__(256) void gemm_kernel(const __hip_bfloat16* __restrict__ A,
                                                   const __hip_bfloat16* __restrict__ B,
                                                   int M, int N, int K,
                                                   const float* __restrict__ aux,
                                                   void* __restrict__ C) {
  __shared__ __align__(16) __hip_bfloat16 As[128 * 32];
  __shared__ __align__(16) __hip_bfloat16 Bs[128 * 32];
  const int tid = threadIdx.x;
  const int lane = tid & 63, w = tid >> 6;
  const int m0 = blockIdx.y * 128, n0 = blockIdx.x * 128;
  const int wm = (w >> 1) * 64, wn = (w & 1) * 64;
  const int r = lane & 15, q = lane >> 4;

  f32x4 acc[4][4];
  const f32x4 zz = {0.f, 0.f, 0.f, 0.f};
  for (int i = 0; i < 4; i++)
    for (int j = 0; j < 4; j++) acc[i][j] = zz;

  for (int k0 = 0; k0 < K; k0 += 32) {
    for (int i = 0; i < 2; i++) {
      const int c = i * 256 + tid;        // 512 chunks of 16B each per matrix
      const int row = c >> 2, kb = (c & 3) * 8;
      gl_lds16(A + (size_t)(m0 + row) * K + (k0 + kb), As + c * 8);
      gl_lds16(B + (size_t)(n0 + row) * K + (k0 + kb), Bs + c * 8);
    }
    __syncthreads();
    bf16x8 af[4], bfr[4];
    for (int mi = 0; mi < 4; mi++)
      af[mi] = *(const bf16x8*)(As + (wm + mi * 16 + r) * 32 + q * 8);
    for (int ni = 0; ni < 4; ni++)
      bfr[ni] = *(const bf16x8*)(Bs + (wn + ni * 16 + r) * 32 + q * 8);
    for (int mi = 0; mi < 4; mi++)
      for (int ni = 0; ni < 4; ni++)
        acc[mi][ni] = __builtin_amdgcn_mfma_f32_16x16x32_bf16(af[mi], bfr[ni], acc[mi][ni], 0, 0, 0);
    __syncthreads();
  }

  for (int mi = 0; mi < 4; mi++)
    for (int ni = 0; ni < 4; ni++)
      for (int j = 0; j < 4; j++) {
        const int gm = m0 + wm + mi * 16 + q * 4 + j;
        const int gn = n0 + wn + ni * 16 + r;
        float v = acc[mi][ni][j];
        const size_t idx = (size_t)gm * N + gn;
        if (EPI == 0) {
          ((__hip_bfloat16*)C)[idx] = f2bf(v);
        } else if (EPI == 1) {
          ((float*)C)[idx] = v + aux[idx];
        } else if (EPI == 2) {
          v = v / (1.0f + expf(-v));
          ((__hip_bfloat16*)C)[idx] = f2bf(v);
        } else {
          ((float*)C)[idx] = v + aux[idx];
        }
      }
}

// ---------------- Flash attention with causal + temporal-decay bias ----------------
// grid: (L/64, B*H); block 256 = 4 waves; wave w owns 16 q-rows.
__global__ __launch_bounds__(256) void attn_kernel(const __hip_bfloat16* __restrict__ qkv,
                                                   const float* __restrict__ ts,
                                                   const float* __restrict__ mask,
                                                   const float* __restrict__ decay_rate,
                                                   __hip_bfloat16* __restrict__ out) {
  const int bh = blockIdx.y;
  const int b = bh >> 3, h = bh & 7;
  const int l0 = blockIdx.x * 64;
  const int tid = threadIdx.x, lane = tid & 63, w = tid >> 6;
  const int lw0 = l0 + w * 16;
  const int r = lane & 15, q = lane >> 4;

  __shared__ __align__(16) __hip_bfloat16 Vt[64 * 32];     // [dh][key] transposed V tile
  __shared__ __align__(16) __hip_bfloat16 Pl[4][16 * 32];  // per-wave P tile [m][key]

  const float decay = log1pf(expf(decay_rate[h]));
  const float scale = 0.125f;   // dh^-0.5
  const float inv24 = 1.0f / 24.0f;

  // Q fragment (A-layout): row = lane&15, k contiguous 8
  bf16x8 qf[2];
  {
    const __hip_bfloat16* qrow = qkv + (size_t)(b * L_SEQ + lw0 + r) * QKV_LD + h * 64 + q * 8;
    qf[0] = *(const bf16x8*)(qrow);
    qf[1] = *(const bf16x8*)(qrow + 32);
  }
  float tq[4];
  for (int j = 0; j < 4; j++) tq[j] = ts[b * L_SEQ + lw0 + q * 4 + j];

  const f32x4 zz = {0.f, 0.f, 0.f, 0.f};
  f32x4 o[4];
  for (int c = 0; c < 4; c++) o[c] = zz;
  float m_r[4], l_r[4];
  for (int j = 0; j < 4; j++) { m_r[j] = -INFINITY; l_r[j] = 0.f; }

  const int ntiles = (l0 >> 5) + 2;  // keys 0 .. l0+63
  for (int kt = 0; kt < ntiles; kt++) {
    const int key0 = kt * 32;
    // stage V^T tile (32 keys x 64 dh) into LDS
    {
      const int kl = tid >> 3, d0 = (tid & 7) * 8;
      const __hip_bfloat16* vsrc =
          qkv + (size_t)(b * L_SEQ + key0 + kl) * QKV_LD + 1024 + h * 64 + d0;
      bf16x8 vv = *(const bf16x8*)vsrc;
      for (int j = 0; j < 8; j++) Vt[(d0 + j) * 32 + kl] = ((const __hip_bfloat16*)&vv)[j];
    }
    __syncthreads();

    // S = Q K^T for two 16-key halves
    f32x4 s[2];
    for (int hc = 0; hc < 2; hc++) {
      const __hip_bfloat16* krow =
          qkv + (size_t)(b * L_SEQ + key0 + hc * 16 + r) * QKV_LD + 512 + h * 64 + q * 8;
      bf16x8 kf0 = *(const bf16x8*)(krow);
      bf16x8 kf1 = *(const bf16x8*)(krow + 32);
      f32x4 a = zz;
      a = __builtin_amdgcn_mfma_f32_16x16x32_bf16(qf[0], kf0, a, 0, 0, 0);
      a = __builtin_amdgcn_mfma_f32_16x16x32_bf16(qf[1], kf1, a, 0, 0, 0);
      s[hc] = a;
    }

    float tk[2], mk[2];
    for (int hc = 0; hc < 2; hc++) {
      const int col = key0 + hc * 16 + r;
      tk[hc] = ts[b * L_SEQ + col];
      mk[hc] = mask[b * L_SEQ + col];
    }

    float p[2][4];
    for (int j = 0; j < 4; j++) {
      const int rowg = lw0 + q * 4 + j;
      float lg[2];
      float best = -INFINITY;
      for (int hc = 0; hc < 2; hc++) {
        const int col = key0 + hc * 16 + r;
        float v = s[hc][j] * scale - decay * fabsf(tq[j] - tk[hc]) * inv24;
        if (col > rowg || mk[hc] == 0.f) v = -INFINITY;
        lg[hc] = v;
        best = fmaxf(best, v);
      }
      for (int off = 1; off < 16; off <<= 1) best = fmaxf(best, __shfl_xor(best, off));
      const float mnew = fmaxf(m_r[j], best);   // finite for all rows from tile 0 onward
      float psum = 0.f;
      for (int hc = 0; hc < 2; hc++) {
        const float e = expf(lg[hc] - mnew);
        p[hc][j] = e;
        psum += e;
      }
      for (int off = 1; off < 16; off <<= 1) psum += __shfl_xor(psum, off);
      const float alpha = expf(m_r[j] - mnew);
      l_r[j] = l_r[j] * alpha + psum;
      m_r[j] = mnew;
      for (int c = 0; c < 4; c++) o[c][j] *= alpha;
    }

    // P: C-layout -> LDS -> A-layout
    for (int hc = 0; hc < 2; hc++)
      for (int j = 0; j < 4; j++)
        Pl[w][(q * 4 + j) * 32 + hc * 16 + r] = f2bf(p[hc][j]);
    __syncthreads();

    bf16x8 pf = *(const bf16x8*)(&Pl[w][r * 32 + q * 8]);
    for (int c = 0; c < 4; c++) {
      bf16x8 vf = *(const bf16x8*)(Vt + (c * 16 + r) * 32 + q * 8);
      o[c] = __builtin_amdgcn_mfma_f32_16x16x32_bf16(pf, vf, o[c], 0, 0, 0);
    }
    __syncthreads();
  }

  for (int c = 0; c < 4; c++)
    for (int j = 0; j < 4; j++) {
      const int rowg = lw0 + q * 4 + j;
      const float v = o[c][j] / l_r[j];
      out[(size_t)(b * L_SEQ + rowg) * D_MODEL + h * 64 + c * 16 + r] = f2bf(v);
    }
}

// ---------------- Launch ----------------
extern "C" void kernel_launch(void* const* d_in, const int* in_sizes, int n_in,
                              void* d_out, int out_size, void* d_ws, size_t ws_size,
                              hipStream_t stream) {
  const float* x = (const float*)d_in[0];
  const float* ts = (const float*)d_in[1];
  const float* mask = (const float*)d_in[2];
  const float* ln1_g = (const float*)d_in[3];
  const float* ln1_b = (const float*)d_in[4];
  const float* w_qkv = (const float*)d_in[5];
  const float* w_out = (const float*)d_in[6];
  const float* decay = (const float*)d_in[7];
  const float* ln2_g = (const float*)d_in[8];
  const float* ln2_b = (const float*)d_in[9];
  const float* w_ff1 = (const float*)d_in[10];
  const float* w_ff2 = (const float*)d_in[11];

  char* ws = (char*)d_ws;
  // layout (bytes), 2MB-granular:
  //   [0, 6M)    weights bf16: wqkv 1.5M, wout 0.5M, wff1 2M, wff2 2M
  //   [6M, 14M)  xn (bf16, dead after gemm0)       } ff1out (32MB, bf16)
  //   [14M, 38M) qkv (bf16, dead after attn)       } overlays [6M, 38M)
  //   [38M, 46M) attnout (bf16) -> reused as h
  //   [46M, 62M) x2 (fp32)
  __hip_bfloat16* wqkv_b = (__hip_bfloat16*)(ws + 0);
  __hip_bfloat16* wout_b = (__hip_bfloat16*)(ws + 1572864);
  __hip_bfloat16* wff1_b = (__hip_bfloat16*)(ws + 2097152);
  __hip_bfloat16* wff2_b = (__hip_bfloat16*)(ws + 4194304);
  __hip_bfloat16* xn = (__hip_bfloat16*)(ws + 6291456);
  __hip_bfloat16* qkv = (__hip_bfloat16*)(ws + 14680064);
  __hip_bfloat16* attnout = (__hip_bfloat16*)(ws + 39845888);
  __hip_bfloat16* h = attnout;  // reuse after attnout is consumed
  __hip_bfloat16* ff1out = (__hip_bfloat16*)(ws + 6291456);
  float* x2 = (float*)(ws + 48234496);
  float* out = (float*)d_out;

  const int M = 2 * L_SEQ;  // 8192

  cvt_kernel<<<dim3(768), dim3(256), 0, stream>>>(w_qkv, wqkv_b, 196608);
  cvt_kernel<<<dim3(256), dim3(256), 0, stream>>>(w_out, wout_b, 65536);
  cvt_kernel<<<dim3(1024), dim3(256), 0, stream>>>(w_ff1, wff1_b, 262144);
  cvt_kernel<<<dim3(1024), dim3(256), 0, stream>>>(w_ff2, wff2_b, 262144);

  ln_kernel<<<dim3(M), dim3(256), 0, stream>>>(x, ln1_g, ln1_b, xn);
  gemm_kernel<0><<<dim3(12, 64), dim3(256), 0, stream>>>(xn, wqkv_b, M, 1536, 512, nullptr, qkv);
  attn_kernel<<<dim3(64, 16), dim3(256), 0, stream>>>(qkv, ts, mask, decay, attnout);
  gemm_kernel<1><<<dim3(4, 64), dim3(256), 0, stream>>>(attnout, wout_b, M, 512, 512, x, x2);
  ln_kernel<<<dim3(M), dim3(256), 0, stream>>>(x2, ln2_g, ln2_b, h);
  gemm_kernel<2><<<dim3(16, 64), dim3(256), 0, stream>>>(h, wff1_b, M, 2048, 512, nullptr, ff1out);
  gemm_kernel<3><<<dim3(4, 64), dim3(256), 0, stream>>>(ff1out, wff2_b, M, 512, 2048, x2, out);
}